// Round 6
// baseline (1683.976 us; speedup 1.0000x reference)
//
#include <hip/hip_runtime.h>
#include <hip/hip_bf16.h>

// Problem constants (fixed by reference)
#define NN 4096      // nodes
#define EE 16384     // edges
#define GG 128       // graphs
#define EDIM 16      // edge_dim
#define HD 4096      // edge-MLP width = 64*64

// Factorized-algorithm tiling (R6: 16-wave / 1024-thread blocks, o-split kk
// pairs, MAXTW=3 -> ~128 regs/wave -> 4 waves/SIMD; raw barriers + dist-2
// hB prefetch from R5)
#define NGROUPS 64       // node groups (64 nodes each)
#define GK 8             // k-chunks (one 4MB W2q slice per XCD)
#define KSUBS 64         // 8-k sub-iterations per block
#define MAXT 40          // max 16-slot edge tiles per group
#define MAXSLOT (MAXT * 16)
#define MAXTW 3          // max tiles per wave (16 waves, 48 >= MAXT)
#define SYHALF (64 * 64 * 8)  // shorts per sY buffer (64 KB)
#define PANEL (8 * 64 * 64)   // W2q shorts per su (per-lane-contiguous layout)

typedef __attribute__((ext_vector_type(8))) short short8;
typedef __attribute__((ext_vector_type(4))) float float4v;

static __device__ inline unsigned short f2b(float f) {
    unsigned u = __float_as_uint(f);
    unsigned r = u + 0x7fff + ((u >> 16) & 1);   // RNE
    return (unsigned short)(r >> 16);
}

static __device__ inline unsigned pk2(float a, float b) {
    __hip_bfloat162 p = __float22bfloat162_rn(make_float2(a, b));
    return *(unsigned*)&p;
}

// ---------------------------------------------------------------------------
// h = relu(ea @ w1 + b1) -> bf16 [EE][HD]   (row EE of hB is a zero row,
// memset once per launch, used as the target of empty-slot gathers)
// ---------------------------------------------------------------------------
__global__ void hker(const float* __restrict__ ea, const float* __restrict__ w1,
                     const float* __restrict__ b1, unsigned short* __restrict__ hB) {
    __shared__ float sea[16 * 16];
    const int tid = threadIdx.x;
    const int j = blockIdx.x * 256 + tid;
    const int e0 = blockIdx.y * 16;
    float w[16];
#pragma unroll
    for (int k = 0; k < 16; ++k) w[k] = w1[k * HD + j];
    const float b = b1[j];
    sea[tid] = ea[e0 * EDIM + tid];
    __syncthreads();
#pragma unroll 4
    for (int el = 0; el < 16; ++el) {
        float a = b;
#pragma unroll
        for (int k = 0; k < 16; ++k) a += sea[el * 16 + k] * w[k];
        hB[(size_t)(e0 + el) * HD + j] = f2b(fmaxf(a, 0.f));
    }
}

// ---------------------------------------------------------------------------
// W2q permute, su-contiguous per (reader kk, lane):
//   W2q[ ((ss*8 + kk)*64 + lane)*64 + (tt*2+q2)*8 + t ]
//     = bf16( w2[k*HD + (q2*32+quad*8+t)*64 + o] )   with k = ss*8+kk,
//       lane = quad*16+lm, o = tt*16+lm.
// ---------------------------------------------------------------------------
__global__ void wperm(const float* __restrict__ w2, unsigned short* __restrict__ W2q) {
    __shared__ float t[64 * 65];
    const int k = blockIdx.x;
    const int tid = threadIdx.x;
    const int o = tid & 63, r4 = tid >> 6;
#pragma unroll
    for (int it = 0; it < 16; ++it) {
        int i = it * 4 + r4;
        t[i * 65 + o] = w2[(size_t)k * HD + i * 64 + o];
    }
    __syncthreads();
    const int o2 = tid >> 2, q = tid & 3;
    const int q2 = q >> 1;
    const int j0 = (o2 >> 4) * 2 + q2;     // fragment slot j = tt*2+q2
    const int lmm = o2 & 15;
    const int blk = k;                      // = ss*8 + kk
#pragma unroll
    for (int cc = 0; cc < 2; ++cc) {
        const int quad = (q & 1) * 2 + cc;
        const int ib = q * 16 + cc * 8;     // i-base = q2*32 + quad*8
        size_t base = ((size_t)(blk * 64 + quad * 16 + lmm)) * 64 + j0 * 8;
        unsigned b0 = pk2(t[(ib + 0) * 65 + o2], t[(ib + 1) * 65 + o2]);
        unsigned b1 = pk2(t[(ib + 2) * 65 + o2], t[(ib + 3) * 65 + o2]);
        unsigned b2_ = pk2(t[(ib + 4) * 65 + o2], t[(ib + 5) * 65 + o2]);
        unsigned b3 = pk2(t[(ib + 6) * 65 + o2], t[(ib + 7) * 65 + o2]);
        *(uint4*)(&W2q[base]) = make_uint4(b0, b1, b2_, b3);
    }
}

// ---------------------------------------------------------------------------
// Edge bucketing (structure fixed per launch; rebuilt every call)
// ---------------------------------------------------------------------------
__global__ void count_edges(const int* __restrict__ src, const int* __restrict__ dst,
                            int* __restrict__ cnt_src, float* __restrict__ cnt_dst) {
    const int e = blockIdx.x * 256 + threadIdx.x;
    atomicAdd(&cnt_src[src[e]], 1);
    atomicAdd(&cnt_dst[dst[e]], 1.f);
}

__global__ void build_layout(const int* __restrict__ cnt_src, int* __restrict__ node_slot_base,
                             int* __restrict__ tile_cluster, int* __restrict__ group_ntiles) {
    const int g = threadIdx.x;        // 0..63, 64-node groups
    int nt = 0;
    int slot = g * MAXSLOT;
    for (int c = 0; c < 16; ++c) {    // 16 clusters of 4 nodes
        int d = 0;
        for (int j = 0; j < 4; ++j) {
            int n = g * 64 + c * 4 + j;
            node_slot_base[n] = slot + d;
            d += cnt_src[n];
        }
        int tcnt = (d + 15) >> 4;
        if (nt + tcnt > MAXT) tcnt = MAXT - nt;   // safety clamp
        for (int j = 0; j < tcnt; ++j) tile_cluster[g * MAXT + nt + j] = c;
        nt += tcnt;
        slot += tcnt * 16;
    }
    group_ntiles[g] = nt;
}

__global__ void fill_slots(const int* __restrict__ src, const int* __restrict__ dst,
                           int* __restrict__ fill, const int* __restrict__ node_slot_base,
                           int* __restrict__ slot_info) {
    const int e = blockIdx.x * 256 + threadIdx.x;
    const int n = src[e];
    const int pos = atomicAdd(&fill[n], 1);
    const int s = node_slot_base[n] + pos;
    const int g = n >> 6;             // 64 nodes/group
    if (s < g * MAXSLOT + MAXSLOT)
        slot_info[s] = e | ((n & 3) << 14) | (dst[e] << 16);
}

// ---------------------------------------------------------------------------
// xb[n,o] = sum_i x[n,i]*b2[i*64+o]; then scatter to agg (bias term of theta)
// ---------------------------------------------------------------------------
__global__ void xb_ker(const float* __restrict__ xcur, const float* __restrict__ b2,
                       float* __restrict__ xb) {
    const int n = blockIdx.x * 4 + (threadIdx.x >> 6);
    const int o = threadIdx.x & 63;
    float a = 0.f;
#pragma unroll
    for (int i = 0; i < 64; ++i) a += xcur[n * 64 + i] * b2[i * 64 + o];
    xb[n * 64 + o] = a;
}

__global__ void b2scatter(const float* __restrict__ xb, const int* __restrict__ src,
                          const int* __restrict__ dst, float* __restrict__ agg) {
    const int e = blockIdx.x * 4 + (threadIdx.x >> 6);
    const int o = threadIdx.x & 63;
    atomicAdd(&agg[(size_t)dst[e] * 64 + o], xb[(size_t)src[e] * 64 + o]);
}

// ---------------------------------------------------------------------------
// Fused factorized kernel — 16-wave / 1024-thread blocks, 64-node groups.
//   wave = (kk = wave>>1, sh = wave&1).  Phase 1: wave computes y for its kk
//   over ALL 4 node-blocks s but only o-half sh (tt = sh*2 + t2) -> BF is 4
//   fragments/wave (total W2q traffic unchanged vs 8-wave).  Phase 2: tiles
//   ti = wave + ai*16, MAXTW=3 -> acc2 = 48 regs.  Target ~128 regs/wave ->
//   4 waves/SIMD (2x R5 occupancy), enforced by __launch_bounds__(1024, 4).
//   Raw barrier (lgkmcnt-only wait) per su; W2q reload post-barrier; hB
//   gather at distance 2.  sY unit layout (verified R5):
//   U(clqg,o) = o*64 + (clqg ^ (o&7)), clqg = cluster*4 + qg, shorts
//   [half*4 + np] with kk = 2*qg + half.
// ---------------------------------------------------------------------------
__global__ __launch_bounds__(1024, 4)
void ygemm_msg(const float* __restrict__ xcur, const unsigned short* __restrict__ hB,
               const unsigned short* __restrict__ W2q, const int* __restrict__ slot_info,
               const int* __restrict__ tile_cluster, const int* __restrict__ group_ntiles,
               float* __restrict__ agg) {
    __shared__ __align__(16) unsigned short sA[64 * 72];        // 9 KB
    __shared__ __align__(16) unsigned short sY[2 * SYHALF];     // 128 KB double buffer

    const int bid = blockIdx.x;
    const int g = bid >> 3;
    const int kc = bid & 7;
    const int tid = threadIdx.x;
    const int lane = tid & 63, wave = tid >> 6;    // wave 0..15
    const int quad = lane >> 4, lm = lane & 15;
    const int kk = wave >> 1, sh = wave & 1;       // k-slice, o-half
    const int qg = kk >> 1, half = kk & 1;

    // stage x group (64 nodes x 64 i) as bf16 (1024 threads: 4 floats each)
    {
        const int n = tid >> 4, ib = (tid & 15) * 4;
        const float* xp = xcur + (size_t)(g * 64 + n) * 64 + ib;
        uint2 w = make_uint2(pk2(xp[0], xp[1]), pk2(xp[2], xp[3]));
        *(uint2*)(&sA[n * 72 + ib]) = w;
    }

    const int ntiles = group_ntiles[g];
    // Per-tile su-invariant precompute: slot info, gather voffset (empty slots
    // -> zero row EE), sY read base (XOR layout), unpack shift (nl*16).
    int infoR[MAXTW], voff[MAXTW], rbase[MAXTW];
    unsigned shl5[MAXTW];
#pragma unroll
    for (int ai = 0; ai < MAXTW; ++ai) {
        const int ti = wave + ai * 16;
        const int info = (ti < ntiles) ? slot_info[g * MAXSLOT + ti * 16 + lm] : -1;
        const int tc   = (ti < ntiles) ? tile_cluster[g * MAXT + ti] : 0;
        infoR[ai] = info;
        voff[ai]  = ((info >= 0) ? (info & 0x3FFF) : EE) * HD + quad * 2;
        rbase[ai] = lm * 512 + (((tc * 4 + quad) ^ (lm & 7)) << 3);
        shl5[ai]  = (unsigned)(((info >> 14) & 3) * 16);
    }

    float4v acc2[MAXTW][4];
#pragma unroll
    for (int a = 0; a < MAXTW; ++a)
#pragma unroll
        for (int t = 0; t < 4; ++t) {
            acc2[a][t][0] = 0.f; acc2[a][t][1] = 0.f;
            acc2[a][t][2] = 0.f; acc2[a][t][3] = 0.f;
        }

    // phase-1 write base (shorts); s*128 and t2*8192 are immediate offsets
    const int wb = lm * 512 + (((quad * 4 + qg) ^ (lm & 7)) << 3) + half * 4
                 + sh * 16384;   // sh picks tt-half (tt = sh*2 + t2)
    __syncthreads();

    // loop-invariant A-fragments (sA never rewritten): all 4 node-blocks
    short8 af[4][2];
#pragma unroll
    for (int s = 0; s < 4; ++s)
#pragma unroll
        for (int q2 = 0; q2 < 2; ++q2)
            af[s][q2] = *(const short8*)(&sA[(s * 16 + lm) * 72 + q2 * 32 + quad * 8]);

    const float4v z4 = {0.f, 0.f, 0.f, 0.f};   // persistent MFMA C-init source

    // streaming pointers: W2q fragments j = sh*4 + t2*2 + q2 for this kk
    const unsigned short* wp  = W2q + ((size_t)(kc * KSUBS * 8 + kk) * 64 + lane) * 64 + sh * 32;
    const unsigned short* hbk = hB + kc * KSUBS * 8;

    // preload su=0 W2q fragments; su=0 and su=1 hB gathers
    short8 BF[2][2];
#pragma unroll
    for (int t2 = 0; t2 < 2; ++t2) {
        BF[t2][0] = *(const short8*)(wp + (t2 * 2 + 0) * 8);
        BF[t2][1] = *(const short8*)(wp + (t2 * 2 + 1) * 8);
    }
    wp += PANEL;
    unsigned hdA[MAXTW], hdB[MAXTW];
#pragma unroll
    for (int ai = 0; ai < MAXTW; ++ai) {
        hdA[ai] = *(const unsigned*)(hbk + voff[ai]);
        hdB[ai] = *(const unsigned*)(hbk + 8 + voff[ai]);
    }

    int hoff = 16;   // short-offset of su+2's hB columns (clamped at the end)

    auto subody = [&](unsigned (&HDc)[MAXTW], unsigned short* __restrict__ sYp) {
        // ---- phase 1: y panel for (kk, o-half sh), all 4 node-blocks s ----
#pragma unroll
        for (int s = 0; s < 4; ++s) {
            float4v a1[2];
#pragma unroll
            for (int t2 = 0; t2 < 2; ++t2)
                a1[t2] = __builtin_amdgcn_mfma_f32_16x16x32_bf16(af[s][0], BF[t2][0], z4, 0, 0, 0);
#pragma unroll
            for (int t2 = 0; t2 < 2; ++t2)
                a1[t2] = __builtin_amdgcn_mfma_f32_16x16x32_bf16(af[s][1], BF[t2][1], a1[t2], 0, 0, 0);
#pragma unroll
            for (int t2 = 0; t2 < 2; ++t2) {
                uint2 v;
                v.x = pk2(a1[t2][0], a1[t2][1]);
                v.y = pk2(a1[t2][2], a1[t2][3]);
                *(uint2*)(&sYp[wb + s * 128 + t2 * 8192]) = v;
            }
        }

        // RAW barrier: wait only for LDS ops (sY writes); global prefetches
        // stay in flight across the barrier (counted vmcnt at their uses).
        asm volatile("s_waitcnt lgkmcnt(0)" ::: "memory");
        __builtin_amdgcn_s_barrier();

        // ---- W2q fragment reload for su+1 (L2-resident; lead = phase 2) ----
#pragma unroll
        for (int t2 = 0; t2 < 2; ++t2) {
            BF[t2][0] = *(const short8*)(wp + (t2 * 2 + 0) * 8);
            BF[t2][1] = *(const short8*)(wp + (t2 * 2 + 1) * 8);
        }
        wp += PANEL;

        // ---- phase 2: per-tile MFMA from preloaded hd + sY ----
#pragma unroll
        for (int ai = 0; ai < MAXTW; ++ai) {
            if (wave + ai * 16 < ntiles) {                 // wave-uniform
                const unsigned h0 = HDc[ai];
                // place (lo,hi) bf16 pair at halfword nl via 64-bit shifts
                unsigned long long A = (unsigned long long)(h0 & 0xffffu) << shl5[ai];
                unsigned long long B = (unsigned long long)(h0 >> 16) << shl5[ai];
                uint4 aw = make_uint4((unsigned)A, (unsigned)(A >> 32),
                                      (unsigned)B, (unsigned)(B >> 32));
                short8 a2 = *(short8*)&aw;
#pragma unroll
                for (int ot = 0; ot < 4; ++ot) {
                    short8 b2f = *(const short8*)(&sYp[rbase[ai] + ot * 8192]);
                    acc2[ai][ot] = __builtin_amdgcn_mfma_f32_16x16x32_bf16(a2, b2f, acc2[ai][ot], 0, 0, 0);
                }
            }
        }

        // ---- hB gather for su+2 into the just-consumed slot (distance 2) ----
#pragma unroll
        for (int ai = 0; ai < MAXTW; ++ai)
            HDc[ai] = *(const unsigned*)(hbk + hoff + voff[ai]);
        hoff = (hoff < 504) ? hoff + 8 : 504;
        // no trailing barrier: next phase 1 writes the other sY buffer
    };

    for (int su2 = 0; su2 < KSUBS; su2 += 2) {
        subody(hdA, sY);
        subody(hdB, sY + SYHALF);
    }

    // ---- flush: atomicAdd into agg[dst] ----
#pragma unroll
    for (int ai = 0; ai < MAXTW; ++ai) {
        const int ti = wave + ai * 16;
        if (ti < ntiles) {
#pragma unroll
            for (int r = 0; r < 4; ++r) {
                const int inf2 = __shfl(infoR[ai], quad * 4 + r, 64);
                if (inf2 >= 0) {
                    const int d = inf2 >> 16;
#pragma unroll
                    for (int ot = 0; ot < 4; ++ot)
                        atomicAdd(&agg[(size_t)d * 64 + ot * 16 + lm], acc2[ai][ot][r]);
                }
            }
        }
    }
}

// ---------------------------------------------------------------------------
// x_next = relu(agg/cnt + x @ root + bias)
// ---------------------------------------------------------------------------
__global__ void combine(const float* __restrict__ agg, const float* __restrict__ cnt,
                        const float* __restrict__ xcur, const float* __restrict__ root,
                        const float* __restrict__ bias, float* __restrict__ xn) {
    const int n = blockIdx.x * 4 + (threadIdx.x >> 6);
    const int o = threadIdx.x & 63;
    float a = agg[n * 64 + o] / fmaxf(cnt[n], 1.f);
    float r = bias[o];
#pragma unroll
    for (int i = 0; i < 64; ++i) r += xcur[n * 64 + i] * root[i * 64 + o];
    xn[n * 64 + o] = fmaxf(a + r, 0.f);
}

// ---------------------------------------------------------------------------
// global mean pool
// ---------------------------------------------------------------------------
__global__ void pool_accum(const float* __restrict__ x3, const int* __restrict__ batch,
                           float* __restrict__ pool, float* __restrict__ pcnt) {
    const int n = blockIdx.x * 4 + (threadIdx.x >> 6);
    const int o = threadIdx.x & 63;
    const int gi = batch[n];
    atomicAdd(&pool[gi * 64 + o], x3[n * 64 + o]);
    if (o == 0) atomicAdd(&pcnt[gi], 1.f);
}

__global__ void pool_norm(const float* __restrict__ pool, const float* __restrict__ pcnt,
                          float* __restrict__ out) {
    const int idx = blockIdx.x * 256 + threadIdx.x;
    out[idx] = pool[idx] / fmaxf(pcnt[idx >> 6], 1.f);
}

// ---------------------------------------------------------------------------
extern "C" void kernel_launch(void* const* d_in, const int* in_sizes, int n_in,
                              void* d_out, int out_size, void* d_ws, size_t ws_size,
                              hipStream_t stream) {
    const float* x   = (const float*)d_in[0];
    const int*   ei  = (const int*)d_in[1];
    const float* ea  = (const float*)d_in[2];
    const int*   bat = (const int*)d_in[3];
    const int* srcp = ei;
    const int* dstp = ei + EE;

    char* ws = (char*)d_ws;
    size_t off = 0;
    unsigned short* hB  = (unsigned short*)(ws + off); off += (size_t)(EE + 1) * HD * 2; // 128MB + zero row
    unsigned short* W2q = (unsigned short*)(ws + off); off += ((size_t)HD * HD + PANEL) * 2; // 32MB + pad
    int* slot_info      = (int*)(ws + off); off += (size_t)NGROUPS * MAXSLOT * 4;
    int* tile_cluster   = (int*)(ws + off); off += (size_t)NGROUPS * MAXT * 4;
    int* group_ntiles   = (int*)(ws + off); off += 1024;
    int* node_slot_base = (int*)(ws + off); off += (size_t)NN * 4;
    int* cnt_src        = (int*)(ws + off); off += (size_t)NN * 4;   // zeroed
    int* fillc          = (int*)(ws + off); off += (size_t)NN * 4;   // zeroed (contig)
    float* cnt_dst      = (float*)(ws + off); off += (size_t)NN * 4; // zeroed (contig)
    float* agg  = (float*)(ws + off); off += (size_t)NN * 64 * 4;
    float* xb   = (float*)(ws + off); off += (size_t)NN * 64 * 4;
    float* xb0  = (float*)(ws + off); off += (size_t)NN * 64 * 4;
    float* xb1  = (float*)(ws + off); off += (size_t)NN * 64 * 4;
    float* pool = (float*)(ws + off); off += (size_t)GG * 64 * 4;
    float* pcnt = (float*)(ws + off); off += (size_t)GG * 4;

    // ---- bucketing (edge structure fixed; rebuilt each call) ----
    hipMemsetAsync(slot_info, 0xFF, (size_t)NGROUPS * MAXSLOT * 4, stream);   // -1
    hipMemsetAsync(cnt_src, 0, (size_t)NN * 4 * 3, stream);                   // cnt_src+fill+cnt_dst
    hipMemsetAsync(hB + (size_t)EE * HD, 0, (size_t)HD * 2, stream);          // zero row for empty slots
    count_edges<<<EE / 256, 256, 0, stream>>>(srcp, dstp, cnt_src, cnt_dst);
    build_layout<<<1, 64, 0, stream>>>(cnt_src, node_slot_base, tile_cluster, group_ntiles);
    fill_slots<<<EE / 256, 256, 0, stream>>>(srcp, dstp, fillc, node_slot_base, slot_info);

    const float* xcur = x;
    float* xbufs[2] = {xb0, xb1};

    for (int l = 0; l < 3; ++l) {
        const float* w1   = (const float*)d_in[4 + 6 * l + 0];
        const float* b1   = (const float*)d_in[4 + 6 * l + 1];
        const float* w2   = (const float*)d_in[4 + 6 * l + 2];
        const float* b2   = (const float*)d_in[4 + 6 * l + 3];
        const float* root = (const float*)d_in[4 + 6 * l + 4];
        const float* bias = (const float*)d_in[4 + 6 * l + 5];

        wperm<<<HD, 256, 0, stream>>>(w2, W2q);
        hker<<<dim3(HD / 256, EE / 16), 256, 0, stream>>>(ea, w1, b1, hB);
        xb_ker<<<NN / 4, 256, 0, stream>>>(xcur, b2, xb);
        hipMemsetAsync(agg, 0, (size_t)NN * 64 * 4, stream);
        b2scatter<<<EE / 4, 256, 0, stream>>>(xb, srcp, dstp, agg);
        ygemm_msg<<<NGROUPS * GK, 1024, 0, stream>>>(xcur, hB, W2q, slot_info,
                                                     tile_cluster, group_ntiles, agg);
        float* xn = xbufs[l & 1];
        combine<<<NN / 4, 256, 0, stream>>>(agg, cnt_dst, xcur, root, bias, xn);
        xcur = xn;
    }
    hipMemsetAsync(pool, 0, (size_t)GG * 64 * 4 + (size_t)GG * 4, stream); // pool+pcnt contiguous
    pool_accum<<<NN / 4, 256, 0, stream>>>(xcur, bat, pool, pcnt);
    pool_norm<<<GG * 64 / 256, 256, 0, stream>>>(pool, pcnt, (float*)d_out);
}

// Round 7
// 1587.409 us; speedup vs baseline: 1.0608x; 1.0608x over previous
//
#include <hip/hip_runtime.h>
#include <hip/hip_bf16.h>

// Problem constants (fixed by reference)
#define NN 4096      // nodes
#define EE 16384     // edges
#define GG 128       // graphs
#define EDIM 16      // edge_dim
#define HD 4096      // edge-MLP width = 64*64

// Factorized-algorithm tiling (R7: R5 structure + 32-edge tiles consumed by
// mfma_f32_32x32x16_bf16 in phase 2 -> per-edge LDS reads halved)
#define NGROUPS 64       // node groups (64 nodes each)
#define GK 8             // k-chunks (one 4MB W2q slice per XCD)
#define KSUBS 64         // 8-k sub-iterations per block
#define MAXT 30          // max 32-slot edge tiles per group (worst case ~26)
#define MAXSLOT (MAXT * 32)
#define MAXTW 4          // max tiles per wave (8 waves, 32 >= MAXT)
#define SYHALF (64 * 64 * 8)  // shorts per sY buffer (64 KB)
#define PANEL (8 * 64 * 64)   // W2q shorts per su (per-lane-contiguous layout)

typedef __attribute__((ext_vector_type(8))) short short8;
typedef __attribute__((ext_vector_type(4))) float float4v;
typedef __attribute__((ext_vector_type(16))) float float16v;

static __device__ inline unsigned short f2b(float f) {
    unsigned u = __float_as_uint(f);
    unsigned r = u + 0x7fff + ((u >> 16) & 1);   // RNE
    return (unsigned short)(r >> 16);
}

static __device__ inline unsigned pk2(float a, float b) {
    __hip_bfloat162 p = __float22bfloat162_rn(make_float2(a, b));
    return *(unsigned*)&p;
}

// ---------------------------------------------------------------------------
// h = relu(ea @ w1 + b1) -> bf16 [EE][HD]   (row EE of hB is a zero row).
// Column STORE order is bit-swapped within each su-8 group (j bits 1<->2):
// stored order [k0,k1,k4,k5,k2,k3,k6,k7] so a ygemm lane (h = lane>>5) reads
// its 4 h-values {2h,2h+1,4+2h,5+2h} as ONE 8-byte gather at offset h*4.
// ---------------------------------------------------------------------------
__global__ void hker(const float* __restrict__ ea, const float* __restrict__ w1,
                     const float* __restrict__ b1, unsigned short* __restrict__ hB) {
    __shared__ float sea[16 * 16];
    const int tid = threadIdx.x;
    const int j = blockIdx.x * 256 + tid;
    const int e0 = blockIdx.y * 16;
    float w[16];
#pragma unroll
    for (int k = 0; k < 16; ++k) w[k] = w1[k * HD + j];
    const float b = b1[j];
    sea[tid] = ea[e0 * EDIM + tid];
    __syncthreads();
    // permuted store column: swap bits 1 and 2 of (j & 7)
    const int js = (j & ~7) | (j & 1) | ((j & 2) << 1) | ((j & 4) >> 1);
#pragma unroll 4
    for (int el = 0; el < 16; ++el) {
        float a = b;
#pragma unroll
        for (int k = 0; k < 16; ++k) a += sea[el * 16 + k] * w[k];
        hB[(size_t)(e0 + el) * HD + js] = f2b(fmaxf(a, 0.f));
    }
}

// ---------------------------------------------------------------------------
// W2q permute, su-contiguous per (reader kk, lane):
//   W2q[ ((ss*8 + kk)*64 + lane)*64 + (tt*2+q2)*8 + t ]
//     = bf16( w2[k*HD + (q2*32+quad*8+t)*64 + o] )   with k = ss*8+kk,
//       lane = quad*16+lm, o = tt*16+lm.
// ---------------------------------------------------------------------------
__global__ void wperm(const float* __restrict__ w2, unsigned short* __restrict__ W2q) {
    __shared__ float t[64 * 65];
    const int k = blockIdx.x;
    const int tid = threadIdx.x;
    const int o = tid & 63, r4 = tid >> 6;
#pragma unroll
    for (int it = 0; it < 16; ++it) {
        int i = it * 4 + r4;
        t[i * 65 + o] = w2[(size_t)k * HD + i * 64 + o];
    }
    __syncthreads();
    const int o2 = tid >> 2, q = tid & 3;
    const int q2 = q >> 1;
    const int j0 = (o2 >> 4) * 2 + q2;     // fragment slot j = tt*2+q2
    const int lmm = o2 & 15;
    const int blk = k;                      // = ss*8 + kk
#pragma unroll
    for (int cc = 0; cc < 2; ++cc) {
        const int quad = (q & 1) * 2 + cc;
        const int ib = q * 16 + cc * 8;     // i-base = q2*32 + quad*8
        size_t base = ((size_t)(blk * 64 + quad * 16 + lmm)) * 64 + j0 * 8;
        unsigned b0 = pk2(t[(ib + 0) * 65 + o2], t[(ib + 1) * 65 + o2]);
        unsigned b1 = pk2(t[(ib + 2) * 65 + o2], t[(ib + 3) * 65 + o2]);
        unsigned b2_ = pk2(t[(ib + 4) * 65 + o2], t[(ib + 5) * 65 + o2]);
        unsigned b3 = pk2(t[(ib + 6) * 65 + o2], t[(ib + 7) * 65 + o2]);
        *(uint4*)(&W2q[base]) = make_uint4(b0, b1, b2_, b3);
    }
}

// ---------------------------------------------------------------------------
// Edge bucketing (structure fixed per launch; rebuilt every call)
// ---------------------------------------------------------------------------
__global__ void count_edges(const int* __restrict__ src, const int* __restrict__ dst,
                            int* __restrict__ cnt_src, float* __restrict__ cnt_dst) {
    const int e = blockIdx.x * 256 + threadIdx.x;
    atomicAdd(&cnt_src[src[e]], 1);
    atomicAdd(&cnt_dst[dst[e]], 1.f);
}

__global__ void build_layout(const int* __restrict__ cnt_src, int* __restrict__ node_slot_base,
                             int* __restrict__ tile_cluster, int* __restrict__ group_ntiles) {
    const int g = threadIdx.x;        // 0..63, 64-node groups
    int nt = 0;
    int slot = g * MAXSLOT;
    for (int c = 0; c < 16; ++c) {    // 16 clusters of 4 nodes
        int d = 0;
        for (int j = 0; j < 4; ++j) {
            int n = g * 64 + c * 4 + j;
            node_slot_base[n] = slot + d;
            d += cnt_src[n];
        }
        int tcnt = (d + 31) >> 5;     // 32-slot tiles
        if (nt + tcnt > MAXT) tcnt = MAXT - nt;   // safety clamp
        for (int j = 0; j < tcnt; ++j) tile_cluster[g * MAXT + nt + j] = c;
        nt += tcnt;
        slot += tcnt * 32;
    }
    group_ntiles[g] = nt;
}

__global__ void fill_slots(const int* __restrict__ src, const int* __restrict__ dst,
                           int* __restrict__ fill, const int* __restrict__ node_slot_base,
                           int* __restrict__ slot_info) {
    const int e = blockIdx.x * 256 + threadIdx.x;
    const int n = src[e];
    const int pos = atomicAdd(&fill[n], 1);
    const int s = node_slot_base[n] + pos;
    const int g = n >> 6;             // 64 nodes/group
    if (s < g * MAXSLOT + MAXSLOT)
        slot_info[s] = e | ((n & 3) << 14) | (dst[e] << 16);
}

// ---------------------------------------------------------------------------
// xb[n,o] = sum_i x[n,i]*b2[i*64+o]; then scatter to agg (bias term of theta)
// ---------------------------------------------------------------------------
__global__ void xb_ker(const float* __restrict__ xcur, const float* __restrict__ b2,
                       float* __restrict__ xb) {
    const int n = blockIdx.x * 4 + (threadIdx.x >> 6);
    const int o = threadIdx.x & 63;
    float a = 0.f;
#pragma unroll
    for (int i = 0; i < 64; ++i) a += xcur[n * 64 + i] * b2[i * 64 + o];
    xb[n * 64 + o] = a;
}

__global__ void b2scatter(const float* __restrict__ xb, const int* __restrict__ src,
                          const int* __restrict__ dst, float* __restrict__ agg) {
    const int e = blockIdx.x * 4 + (threadIdx.x >> 6);
    const int o = threadIdx.x & 63;
    atomicAdd(&agg[(size_t)dst[e] * 64 + o], xb[(size_t)src[e] * 64 + o]);
}

// ---------------------------------------------------------------------------
// Fused factorized kernel — 8-wave blocks, 64-node groups, R5 loop skeleton.
//   Phase 1 (unchanged from R5): y panel per kk = wave; sY unit layout
//   U(row,o) = o*64 + (row ^ (o&7)), row = cluster*4 + (kk>>1), content
//   shorts [kk&1][nl].  Raw barrier (lgkmcnt-only) per su; W2q reload
//   post-barrier; hB gather at distance 2.
//   Phase 2 (NEW): 32-edge tiles, mfma_f32_32x32x16_bf16.  Per tile per su:
//   2 m-halves x 2 o-halves = 4 MFMA, 4 b128 reads for 32 edges (2x fewer
//   reads per edge than 16x16 tiles).  A-fragment: lane (h=lane>>5, o5)
//   holds h[e_slot(o5), kk in {m*4+2h, m*4+2h+1}] placed at halfword nl.
//   B-fragment = one sY unit at row tc*4 + (m*2+h).
// ---------------------------------------------------------------------------
__global__ __launch_bounds__(512, 2)
void ygemm_msg(const float* __restrict__ xcur, const unsigned short* __restrict__ hB,
               const unsigned short* __restrict__ W2q, const int* __restrict__ slot_info,
               const int* __restrict__ tile_cluster, const int* __restrict__ group_ntiles,
               float* __restrict__ agg) {
    __shared__ __align__(16) unsigned short sA[64 * 72];        // 9 KB
    __shared__ __align__(16) unsigned short sY[2 * SYHALF];     // 128 KB double buffer

    const int bid = blockIdx.x;
    const int g = bid >> 3;
    const int kc = bid & 7;
    const int tid = threadIdx.x;
    const int lane = tid & 63, wave = tid >> 6;    // wave 0..7 (= kk)
    const int quad = lane >> 4, lm = lane & 15;
    const int o5 = lane & 31, hh = lane >> 5;      // phase-2 lane split

    // stage x group (64 nodes x 64 i) as bf16
    {
        const int n = tid >> 3, ib = (tid & 7) * 8;
        const float* xp = xcur + (size_t)(g * 64 + n) * 64 + ib;
        uint4 w = make_uint4(pk2(xp[0], xp[1]), pk2(xp[2], xp[3]),
                             pk2(xp[4], xp[5]), pk2(xp[6], xp[7]));
        *(uint4*)(&sA[n * 72 + ib]) = w;
    }

    const int ntiles = group_ntiles[g];
    // Per-tile su-invariant precompute (32-slot tiles): slot info (slot =
    // o5), gather voffset (8B of permuted h columns at h-half hh; empty ->
    // zero row EE), sY read bases per m-half, unpack shift (nl*16).
    int infoR[MAXTW], voff[MAXTW], rb0[MAXTW], rb1[MAXTW];
    unsigned shl5[MAXTW];
#pragma unroll
    for (int ai = 0; ai < MAXTW; ++ai) {
        const int ti = wave + ai * 8;
        const int info = (ti < ntiles) ? slot_info[g * MAXSLOT + ti * 32 + o5] : -1;
        const int tc   = (ti < ntiles) ? tile_cluster[g * MAXT + ti] : 0;
        infoR[ai] = info;
        voff[ai]  = ((info >= 0) ? (info & 0x3FFF) : EE) * HD + hh * 4;
        rb0[ai] = o5 * 512 + (((tc * 4 + hh)     ^ (o5 & 7)) << 3);
        rb1[ai] = o5 * 512 + (((tc * 4 + 2 + hh) ^ (o5 & 7)) << 3);
        shl5[ai]  = (unsigned)(((info >> 14) & 3) * 16);
    }

    float16v acc2[MAXTW][2];
#pragma unroll
    for (int a = 0; a < MAXTW; ++a)
#pragma unroll
        for (int t = 0; t < 2; ++t)
#pragma unroll
            for (int r = 0; r < 16; ++r) acc2[a][t][r] = 0.f;

    const int qg = wave >> 1, half = wave & 1;
    // phase-1 write base (shorts); s*128 and tt*8192 are immediate offsets
    const int wb = lm * 512 + (((quad * 4 + qg) ^ (lm & 7)) << 3) + half * 4;
    __syncthreads();

    // loop-invariant A-fragments (sA never rewritten)
    short8 af[4][2];
#pragma unroll
    for (int s = 0; s < 4; ++s)
#pragma unroll
        for (int q2 = 0; q2 < 2; ++q2)
            af[s][q2] = *(const short8*)(&sA[(s * 16 + lm) * 72 + q2 * 32 + quad * 8]);

    const float4v z4 = {0.f, 0.f, 0.f, 0.f};   // persistent MFMA C-init source

    // streaming pointers
    const unsigned short* wp  = W2q + ((size_t)(kc * KSUBS * 8 + wave) * 64 + lane) * 64;
    const unsigned short* hbk = hB + kc * KSUBS * 8;

    // preload su=0 W2q fragments; su=0 and su=1 hB gathers
    short8 BF[4][2];
#pragma unroll
    for (int tt = 0; tt < 4; ++tt) {
        BF[tt][0] = *(const short8*)(wp + (tt * 2 + 0) * 8);
        BF[tt][1] = *(const short8*)(wp + (tt * 2 + 1) * 8);
    }
    wp += PANEL;
    uint2 hdA[MAXTW], hdB[MAXTW];
#pragma unroll
    for (int ai = 0; ai < MAXTW; ++ai) {
        hdA[ai] = *(const uint2*)(hbk + voff[ai]);
        hdB[ai] = *(const uint2*)(hbk + 8 + voff[ai]);
    }

    int hoff = 16;   // short-offset of su+2's hB columns (clamped at the end)

    auto subody = [&](uint2 (&HDc)[MAXTW], unsigned short* __restrict__ sYp) {
        // ---- phase 1: y panel (kk = wave), s-sequential to cap registers ----
#pragma unroll
        for (int s = 0; s < 4; ++s) {
            float4v a1[4];
#pragma unroll
            for (int tt = 0; tt < 4; ++tt)
                a1[tt] = __builtin_amdgcn_mfma_f32_16x16x32_bf16(af[s][0], BF[tt][0], z4, 0, 0, 0);
#pragma unroll
            for (int tt = 0; tt < 4; ++tt)
                a1[tt] = __builtin_amdgcn_mfma_f32_16x16x32_bf16(af[s][1], BF[tt][1], a1[tt], 0, 0, 0);
#pragma unroll
            for (int tt = 0; tt < 4; ++tt) {
                uint2 v;
                v.x = pk2(a1[tt][0], a1[tt][1]);
                v.y = pk2(a1[tt][2], a1[tt][3]);
                *(uint2*)(&sYp[wb + s * 128 + tt * 8192]) = v;
            }
        }

        // RAW barrier: wait only for LDS ops (sY writes); global prefetches
        // stay in flight across the barrier (counted vmcnt at their uses).
        asm volatile("s_waitcnt lgkmcnt(0)" ::: "memory");
        __builtin_amdgcn_s_barrier();

        // ---- W2q fragment reload for su+1 (L2-resident; lead = phase 2) ----
#pragma unroll
        for (int tt = 0; tt < 4; ++tt) {
            BF[tt][0] = *(const short8*)(wp + (tt * 2 + 0) * 8);
            BF[tt][1] = *(const short8*)(wp + (tt * 2 + 1) * 8);
        }
        wp += PANEL;

        // ---- phase 2: per-tile 32x32x16 MFMA from preloaded hd + sY ----
#pragma unroll
        for (int ai = 0; ai < MAXTW; ++ai) {
            if (wave + ai * 8 < ntiles) {                  // wave-uniform
                const uint2 hg = HDc[ai];
                // m = 0: h at kk {2hh, 2hh+1} -> shorts of hg.x
                {
                    unsigned long long A = (unsigned long long)(hg.x & 0xffffu) << shl5[ai];
                    unsigned long long B = (unsigned long long)(hg.x >> 16) << shl5[ai];
                    uint4 aw = make_uint4((unsigned)A, (unsigned)(A >> 32),
                                          (unsigned)B, (unsigned)(B >> 32));
                    short8 a2 = *(short8*)&aw;
                    short8 b0 = *(const short8*)(&sYp[rb0[ai]]);
                    acc2[ai][0] = __builtin_amdgcn_mfma_f32_32x32x16_bf16(a2, b0, acc2[ai][0], 0, 0, 0);
                    short8 b1 = *(const short8*)(&sYp[rb0[ai] + 16384]);
                    acc2[ai][1] = __builtin_amdgcn_mfma_f32_32x32x16_bf16(a2, b1, acc2[ai][1], 0, 0, 0);
                }
                // m = 1: h at kk {4+2hh, 5+2hh} -> shorts of hg.y
                {
                    unsigned long long A = (unsigned long long)(hg.y & 0xffffu) << shl5[ai];
                    unsigned long long B = (unsigned long long)(hg.y >> 16) << shl5[ai];
                    uint4 aw = make_uint4((unsigned)A, (unsigned)(A >> 32),
                                          (unsigned)B, (unsigned)(B >> 32));
                    short8 a2 = *(short8*)&aw;
                    short8 b0 = *(const short8*)(&sYp[rb1[ai]]);
                    acc2[ai][0] = __builtin_amdgcn_mfma_f32_32x32x16_bf16(a2, b0, acc2[ai][0], 0, 0, 0);
                    short8 b1 = *(const short8*)(&sYp[rb1[ai] + 16384]);
                    acc2[ai][1] = __builtin_amdgcn_mfma_f32_32x32x16_bf16(a2, b1, acc2[ai][1], 0, 0, 0);
                }
            }
        }

        // ---- hB gather for su+2 into the just-consumed slot (distance 2) ----
#pragma unroll
        for (int ai = 0; ai < MAXTW; ++ai)
            HDc[ai] = *(const uint2*)(hbk + hoff + voff[ai]);
        hoff = (hoff < 504) ? hoff + 8 : 504;
        // no trailing barrier: next phase 1 writes the other sY buffer
    };

    for (int su2 = 0; su2 < KSUBS; su2 += 2) {
        subody(hdA, sY);
        subody(hdB, sY + SYHALF);
    }

    // ---- flush: atomicAdd into agg[dst].  32x32 C/D layout: col = lane&31,
    //      row (= edge slot) = (reg&3) + 8*(reg>>2) + 4*(lane>>5). ----
#pragma unroll
    for (int ai = 0; ai < MAXTW; ++ai) {
        const int ti = wave + ai * 8;
        if (ti < ntiles) {
#pragma unroll
            for (int r = 0; r < 16; ++r) {
                const int slot = (r & 3) + 8 * (r >> 2) + 4 * hh;
                const int inf2 = __shfl(infoR[ai], slot, 64);
                if (inf2 >= 0) {
                    const int d = inf2 >> 16;
                    atomicAdd(&agg[(size_t)d * 64 + o5],      acc2[ai][0][r]);
                    atomicAdd(&agg[(size_t)d * 64 + 32 + o5], acc2[ai][1][r]);
                }
            }
        }
    }
}

// ---------------------------------------------------------------------------
// x_next = relu(agg/cnt + x @ root + bias)
// ---------------------------------------------------------------------------
__global__ void combine(const float* __restrict__ agg, const float* __restrict__ cnt,
                        const float* __restrict__ xcur, const float* __restrict__ root,
                        const float* __restrict__ bias, float* __restrict__ xn) {
    const int n = blockIdx.x * 4 + (threadIdx.x >> 6);
    const int o = threadIdx.x & 63;
    float a = agg[n * 64 + o] / fmaxf(cnt[n], 1.f);
    float r = bias[o];
#pragma unroll
    for (int i = 0; i < 64; ++i) r += xcur[n * 64 + i] * root[i * 64 + o];
    xn[n * 64 + o] = fmaxf(a + r, 0.f);
}

// ---------------------------------------------------------------------------
// global mean pool
// ---------------------------------------------------------------------------
__global__ void pool_accum(const float* __restrict__ x3, const int* __restrict__ batch,
                           float* __restrict__ pool, float* __restrict__ pcnt) {
    const int n = blockIdx.x * 4 + (threadIdx.x >> 6);
    const int o = threadIdx.x & 63;
    const int gi = batch[n];
    atomicAdd(&pool[gi * 64 + o], x3[n * 64 + o]);
    if (o == 0) atomicAdd(&pcnt[gi], 1.f);
}

__global__ void pool_norm(const float* __restrict__ pool, const float* __restrict__ pcnt,
                          float* __restrict__ out) {
    const int idx = blockIdx.x * 256 + threadIdx.x;
    out[idx] = pool[idx] / fmaxf(pcnt[idx >> 6], 1.f);
}

// ---------------------------------------------------------------------------
extern "C" void kernel_launch(void* const* d_in, const int* in_sizes, int n_in,
                              void* d_out, int out_size, void* d_ws, size_t ws_size,
                              hipStream_t stream) {
    const float* x   = (const float*)d_in[0];
    const int*   ei  = (const int*)d_in[1];
    const float* ea  = (const float*)d_in[2];
    const int*   bat = (const int*)d_in[3];
    const int* srcp = ei;
    const int* dstp = ei + EE;

    char* ws = (char*)d_ws;
    size_t off = 0;
    unsigned short* hB  = (unsigned short*)(ws + off); off += (size_t)(EE + 1) * HD * 2; // 128MB + zero row
    unsigned short* W2q = (unsigned short*)(ws + off); off += ((size_t)HD * HD + PANEL) * 2; // 32MB + pad
    int* slot_info      = (int*)(ws + off); off += (size_t)NGROUPS * MAXSLOT * 4;
    int* tile_cluster   = (int*)(ws + off); off += (size_t)NGROUPS * MAXT * 4;
    int* group_ntiles   = (int*)(ws + off); off += 1024;
    int* node_slot_base = (int*)(ws + off); off += (size_t)NN * 4;
    int* cnt_src        = (int*)(ws + off); off += (size_t)NN * 4;   // zeroed
    int* fillc          = (int*)(ws + off); off += (size_t)NN * 4;   // zeroed (contig)
    float* cnt_dst      = (float*)(ws + off); off += (size_t)NN * 4; // zeroed (contig)
    float* agg  = (float*)(ws + off); off += (size_t)NN * 64 * 4;
    float* xb   = (float*)(ws + off); off += (size_t)NN * 64 * 4;
    float* xb0  = (float*)(ws + off); off += (size_t)NN * 64 * 4;
    float* xb1  = (float*)(ws + off); off += (size_t)NN * 64 * 4;
    float* pool = (float*)(ws + off); off += (size_t)GG * 64 * 4;
    float* pcnt = (float*)(ws + off); off += (size_t)GG * 4;

    // ---- bucketing (edge structure fixed; rebuilt each call) ----
    hipMemsetAsync(slot_info, 0xFF, (size_t)NGROUPS * MAXSLOT * 4, stream);   // -1
    hipMemsetAsync(cnt_src, 0, (size_t)NN * 4 * 3, stream);                   // cnt_src+fill+cnt_dst
    hipMemsetAsync(hB + (size_t)EE * HD, 0, (size_t)HD * 2, stream);          // zero row for empty slots
    count_edges<<<EE / 256, 256, 0, stream>>>(srcp, dstp, cnt_src, cnt_dst);
    build_layout<<<1, 64, 0, stream>>>(cnt_src, node_slot_base, tile_cluster, group_ntiles);
    fill_slots<<<EE / 256, 256, 0, stream>>>(srcp, dstp, fillc, node_slot_base, slot_info);

    const float* xcur = x;
    float* xbufs[2] = {xb0, xb1};

    for (int l = 0; l < 3; ++l) {
        const float* w1   = (const float*)d_in[4 + 6 * l + 0];
        const float* b1   = (const float*)d_in[4 + 6 * l + 1];
        const float* w2   = (const float*)d_in[4 + 6 * l + 2];
        const float* b2   = (const float*)d_in[4 + 6 * l + 3];
        const float* root = (const float*)d_in[4 + 6 * l + 4];
        const float* bias = (const float*)d_in[4 + 6 * l + 5];

        wperm<<<HD, 256, 0, stream>>>(w2, W2q);
        hker<<<dim3(HD / 256, EE / 16), 256, 0, stream>>>(ea, w1, b1, hB);
        xb_ker<<<NN / 4, 256, 0, stream>>>(xcur, b2, xb);
        hipMemsetAsync(agg, 0, (size_t)NN * 64 * 4, stream);
        b2scatter<<<EE / 4, 256, 0, stream>>>(xb, srcp, dstp, agg);
        ygemm_msg<<<NGROUPS * GK, 512, 0, stream>>>(xcur, hB, W2q, slot_info,
                                                    tile_cluster, group_ntiles, agg);
        float* xn = xbufs[l & 1];
        combine<<<NN / 4, 256, 0, stream>>>(agg, cnt_dst, xcur, root, bias, xn);
        xcur = xn;
    }
    hipMemsetAsync(pool, 0, (size_t)GG * 64 * 4 + (size_t)GG * 4, stream); // pool+pcnt contiguous
    pool_accum<<<NN / 4, 256, 0, stream>>>(xcur, bat, pool, pcnt);
    pool_norm<<<GG * 64 / 256, 256, 0, stream>>>(pool, pcnt, (float*)d_out);
}